// Round 11
// baseline (132.267 us; speedup 1.0000x reference)
//
#include <hip/hip_runtime.h>
#include <hip/hip_bf16.h>

// Problem constants
#define B_    16
#define C_    512
#define HW_   1024
#define G_    32
#define CPG_  16      // channels per group
#define NH_   4
#define D_    128
#define EPS_  1e-5f
#define SCALE_ 0.08838834764831845f       // 1/sqrt(128)
#define SCALE_L2E_ 0.1275174306f          // SCALE_ * log2(e): softmax done in exp2

typedef short bf16x8 __attribute__((ext_vector_type(8)));
typedef short bf16x4 __attribute__((ext_vector_type(4)));
typedef float f32x4  __attribute__((ext_vector_type(4)));

typedef __attribute__((address_space(3))) unsigned int lds_u32_t;
typedef const __attribute__((address_space(1))) unsigned int glb_u32_t;

__device__ __forceinline__ bf16x8 ld8(const __hip_bfloat16* p) {
    return *reinterpret_cast<const bf16x8*>(p);
}
__device__ __forceinline__ void gload16(const __hip_bfloat16* g, __hip_bfloat16* l) {
    // async global->LDS, 16B per lane; LDS dest = wave-uniform base + lane*16
    __builtin_amdgcn_global_load_lds((glb_u32_t*)(const void*)g,
                                     (lds_u32_t*)(void*)l, 16, 0, 0);
}
__device__ __forceinline__ unsigned pack_bf2(float a, float b) {
    union { __hip_bfloat16 h; unsigned short u; } ua, ub;
    ua.h = __float2bfloat16(a); ub.h = __float2bfloat16(b);
    return ((unsigned)ub.u << 16) | (unsigned)ua.u;
}

// ---------------------------------------------------------------- weights
__global__ __launch_bounds__(256) void convert_w(
    const float* __restrict__ wqkv, const float* __restrict__ wout,
    __hip_bfloat16* __restrict__ wqkv_bf, __hip_bfloat16* __restrict__ wout_bf) {
    const int i = (blockIdx.x * 256 + threadIdx.x) * 4;
    if (i < 3 * C_ * C_) {
        float4 v = *reinterpret_cast<const float4*>(wqkv + i);
        union { bf16x4 s; __hip_bfloat16 h[4]; } u;
        u.h[0] = __float2bfloat16(v.x); u.h[1] = __float2bfloat16(v.y);
        u.h[2] = __float2bfloat16(v.z); u.h[3] = __float2bfloat16(v.w);
        *reinterpret_cast<bf16x4*>(wqkv_bf + i) = u.s;
    }
    if (i < C_ * C_) {
        float4 v = *reinterpret_cast<const float4*>(wout + i);
        union { bf16x4 s; __hip_bfloat16 h[4]; } u;
        u.h[0] = __float2bfloat16(v.x); u.h[1] = __float2bfloat16(v.y);
        u.h[2] = __float2bfloat16(v.z); u.h[3] = __float2bfloat16(v.w);
        *reinterpret_cast<bf16x4*>(wout_bf + i) = u.s;
    }
}

// ---------------------------------------------------------------- groupnorm
__global__ __launch_bounds__(256) void gn_kernel(
    const float* __restrict__ x, const float* __restrict__ gnw,
    const float* __restrict__ gnb, __hip_bfloat16* __restrict__ xn_t) {
    const int b = blockIdx.x >> 5;
    const int g = blockIdx.x & 31;
    const float* xp = x + ((size_t)(b * C_ + g * CPG_)) * HW_;  // 16x1024 contiguous

    float s = 0.f, s2 = 0.f;
    const float4* xv = reinterpret_cast<const float4*>(xp);
    #pragma unroll
    for (int t = 0; t < 16; ++t) {
        float4 v = xv[threadIdx.x + t * 256];
        s  += v.x + v.y + v.z + v.w;
        s2 += v.x * v.x + v.y * v.y + v.z * v.z + v.w * v.w;
    }
    #pragma unroll
    for (int off = 32; off > 0; off >>= 1) {
        s  += __shfl_down(s,  off, 64);
        s2 += __shfl_down(s2, off, 64);
    }
    __shared__ float ss[4], ss2[4];
    if ((threadIdx.x & 63) == 0) { ss[threadIdx.x >> 6] = s; ss2[threadIdx.x >> 6] = s2; }
    __syncthreads();
    s = ss[0] + ss[1] + ss[2] + ss[3];
    s2 = ss2[0] + ss2[1] + ss2[2] + ss2[3];
    const float mean = s * (1.f / 16384.f);
    const float inv  = rsqrtf(fmaxf(s2 * (1.f / 16384.f) - mean * mean, 0.f) + EPS_);

    float a[16], bb[16];
    #pragma unroll
    for (int cc = 0; cc < 16; ++cc) {
        float w = gnw[g * CPG_ + cc];
        a[cc] = inv * w;
        bb[cc] = gnb[g * CPG_ + cc] - mean * inv * w;
    }

    for (int hw = threadIdx.x; hw < HW_; hw += 256) {
        union { bf16x8 v; __hip_bfloat16 h[8]; } u0, u1;
        #pragma unroll
        for (int cc = 0; cc < 8; ++cc)
            u0.h[cc] = __float2bfloat16(xp[cc * HW_ + hw] * a[cc] + bb[cc]);
        #pragma unroll
        for (int cc = 8; cc < 16; ++cc)
            u1.h[cc - 8] = __float2bfloat16(xp[cc * HW_ + hw] * a[cc] + bb[cc]);
        __hip_bfloat16* dst = xn_t + ((size_t)(b * HW_ + hw)) * C_ + g * CPG_;
        *reinterpret_cast<bf16x8*>(dst) = u0.v;
        *reinterpret_cast<bf16x8*>(dst + 8) = u1.v;
    }
}

// swizzled phys element offset: 128-row tile, 8 slots (16B) per row
#define PH_(r, s) (((r) * 8 + ((s) ^ ((r) & 7))) * 8)

// ---------------------------------------------------------------- QKV GEMM
// Double-buffered gload_lds staging (T3 2-phase).
__global__ __launch_bounds__(256, 2) void qkv_gemm(
    const __hip_bfloat16* __restrict__ W, const __hip_bfloat16* __restrict__ xn_t,
    __hip_bfloat16* __restrict__ q_t, __hip_bfloat16* __restrict__ k_t,
    __hip_bfloat16* __restrict__ v_s) {
    const int id   = blockIdx.x;                 // 0..1535
    const int virt = (id & 7) * 192 + (id >> 3); // XCD-chunked remap
    const int ot   = virt % 12;                  // o tile (0-3 Q, 4-7 K, 8-11 V)
    const int rest = virt / 12;
    const int itl  = rest & 7;
    const int b    = rest >> 3;
    const int o0 = ot * 128, i0 = itl * 128;

    const int t = threadIdx.x;
    const int w = t >> 6, lane = t & 63, l16 = lane & 15, lg = lane >> 4;
    const int wr = w >> 1, wc = w & 1;           // wave's 64x64 quadrant
    const __hip_bfloat16* xb = xn_t + (size_t)b * HW_ * C_;

    __shared__ __align__(16) __hip_bfloat16 Ab[2][128 * 64];
    __shared__ __align__(16) __hip_bfloat16 Bb[2][128 * 64];

    // staging: wave w covers rows [w*32, w*32+32), 4 insts of 8 rows each
    const int r8  = lane >> 3;           // row within 8-row chunk
    const int ssl = (lane & 7) ^ r8;     // pre-swizzled source slot (16B units)
    auto issue = [&](int kk, int bi) {
        #pragma unroll
        for (int j = 0; j < 4; ++j) {
            const int row = w * 32 + j * 8 + r8;
            gload16(W  + (size_t)(o0 + row) * C_ + kk + ssl * 8, &Ab[bi][(w * 32 + j * 8) * 64]);
            gload16(xb + (size_t)(i0 + row) * C_ + kk + ssl * 8, &Bb[bi][(w * 32 + j * 8) * 64]);
        }
    };

    f32x4 acc[4][4];
    const f32x4 z = {0.f, 0.f, 0.f, 0.f};
    #pragma unroll
    for (int m = 0; m < 4; ++m)
        #pragma unroll
        for (int n = 0; n < 4; ++n) acc[m][n] = z;

    issue(0, 0);
    for (int ks = 0; ks < 8; ++ks) {
        __syncthreads();   // drains tile-ks loads (only ones outstanding); frees buf^1
        if (ks < 7) issue((ks + 1) * 64, (ks + 1) & 1);   // in flight under compute
        const __hip_bfloat16* Ac = Ab[ks & 1];
        const __hip_bfloat16* Bc = Bb[ks & 1];
        #pragma unroll
        for (int kks = 0; kks < 2; ++kks) {
            bf16x8 af[4], bfr[4];
            #pragma unroll
            for (int m = 0; m < 4; ++m)
                af[m] = ld8(&Ac[PH_(wr * 64 + m * 16 + l16, kks * 4 + lg)]);
            #pragma unroll
            for (int n = 0; n < 4; ++n)
                bfr[n] = ld8(&Bc[PH_(wc * 64 + n * 16 + l16, kks * 4 + lg)]);
            if (ot < 8) {   // Q/K: swapped -> row=i, col(l16)=d
                #pragma unroll
                for (int m = 0; m < 4; ++m)
                    #pragma unroll
                    for (int n = 0; n < 4; ++n)
                        acc[m][n] = __builtin_amdgcn_mfma_f32_16x16x32_bf16(bfr[n], af[m], acc[m][n], 0, 0, 0);
            } else {        // V: normal -> row=d, col(l16)=i
                #pragma unroll
                for (int m = 0; m < 4; ++m)
                    #pragma unroll
                    for (int n = 0; n < 4; ++n)
                        acc[m][n] = __builtin_amdgcn_mfma_f32_16x16x32_bf16(af[m], bfr[n], acc[m][n], 0, 0, 0);
            }
        }
    }

    if (ot < 4) {            // Q (pre-scaled by SCALE*log2e): row(reg)=i, col(l16)=d
        const int hd = ot;
        __hip_bfloat16* base = q_t + (size_t)(b * NH_ + hd) * HW_ * D_;
        const int dd = wr * 64 + l16;
        #pragma unroll
        for (int m = 0; m < 4; ++m)
            #pragma unroll
            for (int n = 0; n < 4; ++n)
                #pragma unroll
                for (int r = 0; r < 4; ++r) {
                    const int i = i0 + wc * 64 + n * 16 + lg * 4 + r;
                    base[(size_t)i * D_ + dd + m * 16] = __float2bfloat16(acc[m][n][r] * SCALE_L2E_);
                }
    } else if (ot < 8) {     // K
        const int hd = ot - 4;
        __hip_bfloat16* base = k_t + (size_t)(b * NH_ + hd) * HW_ * D_;
        const int dd = wr * 64 + l16;
        #pragma unroll
        for (int m = 0; m < 4; ++m)
            #pragma unroll
            for (int n = 0; n < 4; ++n)
                #pragma unroll
                for (int r = 0; r < 4; ++r) {
                    const int i = i0 + wc * 64 + n * 16 + lg * 4 + r;
                    base[(size_t)i * D_ + dd + m * 16] = __float2bfloat16(acc[m][n][r]);
                }
    } else {                 // V: row(reg)=d, col(l16)=i
        const int hd = ot - 8;
        __hip_bfloat16* base = v_s + (size_t)(b * NH_ + hd) * D_ * HW_;
        #pragma unroll
        for (int m = 0; m < 4; ++m)
            #pragma unroll
            for (int r = 0; r < 4; ++r) {
                const int dd = wr * 64 + m * 16 + lg * 4 + r;
                #pragma unroll
                for (int n = 0; n < 4; ++n) {
                    const int i = i0 + wc * 64 + n * 16 + l16;
                    base[(size_t)dd * HW_ + i] = __float2bfloat16(acc[m][n][r]);
                }
            }
    }
}

// ---------------------------------------------------------------- attention
// Swapped QK^T softmax in-register, defer-max, conflict-free P staging.
// R10: V-staging pattern fixed (t>>3 rows, 8 slots -> conflict-free ds_write);
// s_setprio(1) around MFMA clusters (T5).
__global__ __launch_bounds__(512, 4) void attn_kernel(
    const __hip_bfloat16* __restrict__ q_t, const __hip_bfloat16* __restrict__ k_t,
    const __hip_bfloat16* __restrict__ v_s, __hip_bfloat16* __restrict__ at) {
    const int id  = blockIdx.x;            // 0..511
    const int xcd = id & 7;
    const int q8  = id >> 3;               // 0..63
    const int hb  = xcd * 8 + (q8 >> 3);   // all 8 it-tiles of hb on one XCD
    const int it  = q8 & 7;
    const int h   = hb & 3;
    const int b   = hb >> 2;

    const int t = threadIdx.x;
    const int w  = t >> 6;
    const int lane = t & 63;
    const int l16 = lane & 15, lg = lane >> 4;
    const size_t bh = (size_t)b * NH_ + h;
    const __hip_bfloat16* qp = q_t + bh * HW_ * D_;
    const __hip_bfloat16* kp = k_t + bh * HW_ * D_;
    const __hip_bfloat16* vp = v_s + bh * D_ * HW_;
    const int i0 = it * 128 + w * 16;

    __shared__ __align__(16) __hip_bfloat16 kbuf[64 * 128];
    __shared__ __align__(16) __hip_bfloat16 vbuf[128 * 64];
    __shared__ __align__(16) __hip_bfloat16 P2[8][16][72];  // per-wave P rows (q x k)

    #define KPHYS(row, c) (((row) * 16 + ((c) ^ ((row) & 7))) * 8)
    #define VPHYS(row, c) (((row) * 8  + ((c) ^ ((row) & 7))) * 8)

    const int krow = t >> 3, kc = t & 7;
    const int vrow = t >> 3, vc = t & 7;   // V: rows {vrow, vrow+64}, all 8 slots

    bf16x8 kreg0, kreg1, vreg0, vreg1;
    auto issue_loads = [&](int j0) {
        kreg0 = ld8(kp + (size_t)(j0 + krow) * D_ + kc * 8);
        kreg1 = ld8(kp + (size_t)(j0 + krow) * D_ + (kc + 8) * 8);
        vreg0 = ld8(vp + (size_t)vrow * HW_ + j0 + vc * 8);
        vreg1 = ld8(vp + (size_t)(vrow + 64) * HW_ + j0 + vc * 8);
    };

    bf16x8 aq[4];
    #pragma unroll
    for (int kd = 0; kd < 4; ++kd)
        aq[kd] = ld8(qp + (size_t)(i0 + l16) * D_ + kd * 32 + lg * 8);

    f32x4 accO[8];
    const f32x4 z = {0.f, 0.f, 0.f, 0.f};
    #pragma unroll
    for (int tt = 0; tt < 8; ++tt) accO[tt] = z;
    float m_run = -INFINITY;   // per q-row (q = l16), replicated across lg
    float l_run = 0.f;

    issue_loads(0);

    for (int jb = 0; jb < 16; ++jb) {
        __syncthreads();
        *reinterpret_cast<bf16x8*>(&kbuf[KPHYS(krow, kc)])       = kreg0;
        *reinterpret_cast<bf16x8*>(&kbuf[KPHYS(krow, kc + 8)])   = kreg1;
        *reinterpret_cast<bf16x8*>(&vbuf[VPHYS(vrow, vc)])       = vreg0;
        *reinterpret_cast<bf16x8*>(&vbuf[VPHYS(vrow + 64, vc)])  = vreg1;
        __syncthreads();
        if (jb < 15) issue_loads((jb + 1) * 64);

        // ---- swapped QK^T: st[jt][r] = S[k = jt*16+lg*4+r][q = l16]
        f32x4 st[4];
        #pragma unroll
        for (int jt = 0; jt < 4; ++jt) st[jt] = z;
        __builtin_amdgcn_s_setprio(1);
        #pragma unroll
        for (int jt = 0; jt < 4; ++jt)
            #pragma unroll
            for (int kd = 0; kd < 4; ++kd) {
                bf16x8 bk = ld8(&kbuf[KPHYS(jt * 16 + l16, kd * 4 + lg)]);
                st[jt] = __builtin_amdgcn_mfma_f32_16x16x32_bf16(bk, aq[kd], st[jt], 0, 0, 0);
            }
        __builtin_amdgcn_s_setprio(0);

        // ---- in-lane row max (16 values) + cross-lg reduce (2 shuffles)
        float mx = fmaxf(fmaxf(st[0][0], st[0][1]), fmaxf(st[0][2], st[0][3]));
        #pragma unroll
        for (int jt = 1; jt < 4; ++jt)
            mx = fmaxf(mx, fmaxf(fmaxf(st[jt][0], st[jt][1]), fmaxf(st[jt][2], st[jt][3])));
        mx = fmaxf(mx, __shfl_xor(mx, 16, 64));
        mx = fmaxf(mx, __shfl_xor(mx, 32, 64));

        // ---- defer-max: rescale only when tile max exceeds running max + 8
        if (__any(mx > m_run + 8.f)) {
            float mnew = fmaxf(m_run, mx);
            float alpha = exp2f(m_run - mnew);   // 0 on first tile
            m_run = mnew;
            l_run *= alpha;
            float al[4];
            #pragma unroll
            for (int r = 0; r < 4; ++r) al[r] = __shfl(alpha, lg * 4 + r, 64);
            const f32x4 a4 = {al[0], al[1], al[2], al[3]};
            #pragma unroll
            for (int tt = 0; tt < 8; ++tt) accO[tt] *= a4;
        }

        // ---- P = exp2(S - m), accumulate l, pack to LDS (4 b64 writes)
        float sum = 0.f;
        #pragma unroll
        for (int jt = 0; jt < 4; ++jt) {
            float p0 = exp2f(st[jt][0] - m_run), p1 = exp2f(st[jt][1] - m_run);
            float p2 = exp2f(st[jt][2] - m_run), p3 = exp2f(st[jt][3] - m_run);
            sum += (p0 + p1) + (p2 + p3);
            uint2 uu = { pack_bf2(p0, p1), pack_bf2(p2, p3) };
            *reinterpret_cast<uint2*>(&P2[w][l16][jt * 16 + lg * 4]) = uu;
        }
        sum += __shfl_xor(sum, 16, 64);
        sum += __shfl_xor(sum, 32, 64);
        l_run += sum;

        // ---- PV (original orientation: A = P rows(q), B = V rows(d))
        __builtin_amdgcn_s_setprio(1);
        #pragma unroll
        for (int ks = 0; ks < 2; ++ks) {
            bf16x8 pa = ld8(&P2[w][l16][ks * 32 + lg * 8]);
            #pragma unroll
            for (int dt = 0; dt < 8; ++dt) {
                bf16x8 bv = ld8(&vbuf[VPHYS(dt * 16 + l16, ks * 4 + lg)]);
                accO[dt] = __builtin_amdgcn_mfma_f32_16x16x32_bf16(pa, bv, accO[dt], 0, 0, 0);
            }
        }
        __builtin_amdgcn_s_setprio(0);
    }

    const float linv = 1.f / l_run;
    float rl[4];
    #pragma unroll
    for (int r = 0; r < 4; ++r) rl[r] = __shfl(linv, lg * 4 + r, 64);
    #pragma unroll
    for (int r = 0; r < 4; ++r) {
        const int i = i0 + lg * 4 + r;
        #pragma unroll
        for (int dt = 0; dt < 8; ++dt)
            at[((size_t)b * HW_ + i) * C_ + h * D_ + dt * 16 + l16] =
                __float2bfloat16(accO[dt][r] * rl[r]);
    }
    #undef KPHYS
    #undef VPHYS
}

// ---------------------------------------------------------------- out GEMM + bias + residual
// Same double-buffered structure as qkv_gemm.
__global__ __launch_bounds__(256, 2) void out_gemm(
    const __hip_bfloat16* __restrict__ W, const __hip_bfloat16* __restrict__ at,
    const float* __restrict__ b_out, const float* __restrict__ x,
    float* __restrict__ out) {
    const int id   = blockIdx.x;                // 0..511
    const int virt = (id & 7) * 64 + (id >> 3); // XCD-chunked remap
    const int ot   = virt & 3;
    const int rest = virt >> 2;
    const int itl  = rest & 7;
    const int b    = rest >> 3;
    const int o0 = ot * 128, i0 = itl * 128;

    const int t = threadIdx.x;
    const int w = t >> 6, lane = t & 63, l16 = lane & 15, lg = lane >> 4;
    const int wr = w >> 1, wc = w & 1;
    const __hip_bfloat16* ab = at + (size_t)b * HW_ * C_;

    __shared__ __align__(16) __hip_bfloat16 Ab[2][128 * 64];
    __shared__ __align__(16) __hip_bfloat16 Bb[2][128 * 64];

    const int r8  = lane >> 3;
    const int ssl = (lane & 7) ^ r8;
    auto issue = [&](int kk, int bi) {
        #pragma unroll
        for (int j = 0; j < 4; ++j) {
            const int row = w * 32 + j * 8 + r8;
            gload16(W  + (size_t)(o0 + row) * C_ + kk + ssl * 8, &Ab[bi][(w * 32 + j * 8) * 64]);
            gload16(ab + (size_t)(i0 + row) * C_ + kk + ssl * 8, &Bb[bi][(w * 32 + j * 8) * 64]);
        }
    };

    f32x4 acc[4][4];
    const f32x4 z = {0.f, 0.f, 0.f, 0.f};
    #pragma unroll
    for (int m = 0; m < 4; ++m)
        #pragma unroll
        for (int n = 0; n < 4; ++n) acc[m][n] = z;

    issue(0, 0);
    for (int ks = 0; ks < 8; ++ks) {
        __syncthreads();
        if (ks < 7) issue((ks + 1) * 64, (ks + 1) & 1);
        const __hip_bfloat16* Ac = Ab[ks & 1];
        const __hip_bfloat16* Bc = Bb[ks & 1];
        #pragma unroll
        for (int kks = 0; kks < 2; ++kks) {
            bf16x8 af[4], bfr[4];
            #pragma unroll
            for (int m = 0; m < 4; ++m)
                af[m] = ld8(&Ac[PH_(wr * 64 + m * 16 + l16, kks * 4 + lg)]);
            #pragma unroll
            for (int n = 0; n < 4; ++n)
                bfr[n] = ld8(&Bc[PH_(wc * 64 + n * 16 + l16, kks * 4 + lg)]);
            #pragma unroll
            for (int m = 0; m < 4; ++m)
                #pragma unroll
                for (int n = 0; n < 4; ++n)
                    acc[m][n] = __builtin_amdgcn_mfma_f32_16x16x32_bf16(af[m], bfr[n], acc[m][n], 0, 0, 0);
        }
    }

    #pragma unroll
    for (int m = 0; m < 4; ++m)
        #pragma unroll
        for (int r = 0; r < 4; ++r) {
            const int o = o0 + wr * 64 + m * 16 + lg * 4 + r;
            const float bo = b_out[o];
            #pragma unroll
            for (int n = 0; n < 4; ++n) {
                const int i = i0 + wc * 64 + n * 16 + l16;
                const size_t idx = ((size_t)(b * C_ + o)) * HW_ + i;
                out[idx] = acc[m][n][r] + bo + x[idx];
            }
        }
}

// ---------------------------------------------------------------- launch
extern "C" void kernel_launch(void* const* d_in, const int* in_sizes, int n_in,
                              void* d_out, int out_size, void* d_ws, size_t ws_size,
                              hipStream_t stream) {
    (void)in_sizes; (void)n_in; (void)out_size; (void)ws_size;
    const float* x     = (const float*)d_in[0];
    const float* gn_w  = (const float*)d_in[1];
    const float* gn_b  = (const float*)d_in[2];
    const float* w_qkv = (const float*)d_in[3];
    const float* w_out = (const float*)d_in[4];
    const float* b_out = (const float*)d_in[5];
    float* out = (float*)d_out;

    char* ws = (char*)d_ws;
    size_t off = 0;
    auto alloc = [&](size_t bytes) { void* p = ws + off; off += (bytes + 255) & ~255ULL; return p; };
    __hip_bfloat16* wqkv_bf = (__hip_bfloat16*)alloc((size_t)3 * C_ * C_ * 2);
    __hip_bfloat16* wout_bf = (__hip_bfloat16*)alloc((size_t)C_ * C_ * 2);
    __hip_bfloat16* xn_t    = (__hip_bfloat16*)alloc((size_t)B_ * HW_ * C_ * 2);
    __hip_bfloat16* q_t     = (__hip_bfloat16*)alloc((size_t)B_ * HW_ * C_ * 2);
    __hip_bfloat16* k_t     = (__hip_bfloat16*)alloc((size_t)B_ * HW_ * C_ * 2);
    __hip_bfloat16* v_s     = (__hip_bfloat16*)alloc((size_t)B_ * HW_ * C_ * 2);
    __hip_bfloat16* at      = xn_t;  // alias: xn_t dead after qkv_gemm

    convert_w<<<768, 256, 0, stream>>>(w_qkv, w_out, wqkv_bf, wout_bf);
    gn_kernel<<<512, 256, 0, stream>>>(x, gn_w, gn_b, xn_t);
    qkv_gemm<<<1536, 256, 0, stream>>>(wqkv_bf, xn_t, q_t, k_t, v_s);
    attn_kernel<<<512, 512, 0, stream>>>(q_t, k_t, v_s, at);
    out_gemm<<<512, 256, 0, stream>>>(wout_bf, at, b_out, x, out);
}

// Round 13
// 125.010 us; speedup vs baseline: 1.0581x; 1.0581x over previous
//
#include <hip/hip_runtime.h>
#include <hip/hip_bf16.h>

// Problem constants
#define B_    16
#define C_    512
#define HW_   1024
#define G_    32
#define CPG_  16      // channels per group
#define NH_   4
#define D_    128
#define EPS_  1e-5f
#define SCALE_ 0.08838834764831845f       // 1/sqrt(128)
#define SCALE_L2E_ 0.1275174306f          // SCALE_ * log2(e): softmax done in exp2

typedef short bf16x8 __attribute__((ext_vector_type(8)));
typedef short bf16x4 __attribute__((ext_vector_type(4)));
typedef float f32x4  __attribute__((ext_vector_type(4)));
typedef float f32x16 __attribute__((ext_vector_type(16)));

typedef __attribute__((address_space(3))) unsigned int lds_u32_t;
typedef const __attribute__((address_space(1))) unsigned int glb_u32_t;

__device__ __forceinline__ bf16x8 ld8(const __hip_bfloat16* p) {
    return *reinterpret_cast<const bf16x8*>(p);
}
__device__ __forceinline__ void gload16(const __hip_bfloat16* g, __hip_bfloat16* l) {
    __builtin_amdgcn_global_load_lds((glb_u32_t*)(const void*)g,
                                     (lds_u32_t*)(void*)l, 16, 0, 0);
}
__device__ __forceinline__ unsigned cvtpk_bf16(float lo, float hi) {
    unsigned r;
    asm("v_cvt_pk_bf16_f32 %0, %1, %2" : "=v"(r) : "v"(lo), "v"(hi));
    return r;
}

// ---------------------------------------------------------------- weights
__global__ __launch_bounds__(256) void convert_w(
    const float* __restrict__ wqkv, const float* __restrict__ wout,
    __hip_bfloat16* __restrict__ wqkv_bf, __hip_bfloat16* __restrict__ wout_bf) {
    const int i = (blockIdx.x * 256 + threadIdx.x) * 4;
    if (i < 3 * C_ * C_) {
        float4 v = *reinterpret_cast<const float4*>(wqkv + i);
        union { bf16x4 s; __hip_bfloat16 h[4]; } u;
        u.h[0] = __float2bfloat16(v.x); u.h[1] = __float2bfloat16(v.y);
        u.h[2] = __float2bfloat16(v.z); u.h[3] = __float2bfloat16(v.w);
        *reinterpret_cast<bf16x4*>(wqkv_bf + i) = u.s;
    }
    if (i < C_ * C_) {
        float4 v = *reinterpret_cast<const float4*>(wout + i);
        union { bf16x4 s; __hip_bfloat16 h[4]; } u;
        u.h[0] = __float2bfloat16(v.x); u.h[1] = __float2bfloat16(v.y);
        u.h[2] = __float2bfloat16(v.z); u.h[3] = __float2bfloat16(v.w);
        *reinterpret_cast<bf16x4*>(wout_bf + i) = u.s;
    }
}

// ---------------------------------------------------------------- groupnorm
__global__ __launch_bounds__(256) void gn_kernel(
    const float* __restrict__ x, const float* __restrict__ gnw,
    const float* __restrict__ gnb, __hip_bfloat16* __restrict__ xn_t) {
    const int b = blockIdx.x >> 5;
    const int g = blockIdx.x & 31;
    const float* xp = x + ((size_t)(b * C_ + g * CPG_)) * HW_;  // 16x1024 contiguous

    float s = 0.f, s2 = 0.f;
    const float4* xv = reinterpret_cast<const float4*>(xp);
    #pragma unroll
    for (int t = 0; t < 16; ++t) {
        float4 v = xv[threadIdx.x + t * 256];
        s  += v.x + v.y + v.z + v.w;
        s2 += v.x * v.x + v.y * v.y + v.z * v.z + v.w * v.w;
    }
    #pragma unroll
    for (int off = 32; off > 0; off >>= 1) {
        s  += __shfl_down(s,  off, 64);
        s2 += __shfl_down(s2, off, 64);
    }
    __shared__ float ss[4], ss2[4];
    if ((threadIdx.x & 63) == 0) { ss[threadIdx.x >> 6] = s; ss2[threadIdx.x >> 6] = s2; }
    __syncthreads();
    s = ss[0] + ss[1] + ss[2] + ss[3];
    s2 = ss2[0] + ss2[1] + ss2[2] + ss2[3];
    const float mean = s * (1.f / 16384.f);
    const float inv  = rsqrtf(fmaxf(s2 * (1.f / 16384.f) - mean * mean, 0.f) + EPS_);

    float a[16], bb[16];
    #pragma unroll
    for (int cc = 0; cc < 16; ++cc) {
        float w = gnw[g * CPG_ + cc];
        a[cc] = inv * w;
        bb[cc] = gnb[g * CPG_ + cc] - mean * inv * w;
    }

    for (int hw = threadIdx.x; hw < HW_; hw += 256) {
        union { bf16x8 v; __hip_bfloat16 h[8]; } u0, u1;
        #pragma unroll
        for (int cc = 0; cc < 8; ++cc)
            u0.h[cc] = __float2bfloat16(xp[cc * HW_ + hw] * a[cc] + bb[cc]);
        #pragma unroll
        for (int cc = 8; cc < 16; ++cc)
            u1.h[cc - 8] = __float2bfloat16(xp[cc * HW_ + hw] * a[cc] + bb[cc]);
        __hip_bfloat16* dst = xn_t + ((size_t)(b * HW_ + hw)) * C_ + g * CPG_;
        *reinterpret_cast<bf16x8*>(dst) = u0.v;
        *reinterpret_cast<bf16x8*>(dst + 8) = u1.v;
    }
}

// swizzled phys element offset: 128-row tile, 8 slots (16B) per row
#define PH_(r, s) (((r) * 8 + ((s) ^ ((r) & 7))) * 8)

// ---------------------------------------------------------------- QKV GEMM
// Double-buffered gload_lds staging (T3 2-phase).
__global__ __launch_bounds__(256, 2) void qkv_gemm(
    const __hip_bfloat16* __restrict__ W, const __hip_bfloat16* __restrict__ xn_t,
    __hip_bfloat16* __restrict__ q_t, __hip_bfloat16* __restrict__ k_t,
    __hip_bfloat16* __restrict__ v_s) {
    const int id   = blockIdx.x;                 // 0..1535
    const int virt = (id & 7) * 192 + (id >> 3); // XCD-chunked remap
    const int ot   = virt % 12;                  // o tile (0-3 Q, 4-7 K, 8-11 V)
    const int rest = virt / 12;
    const int itl  = rest & 7;
    const int b    = rest >> 3;
    const int o0 = ot * 128, i0 = itl * 128;

    const int t = threadIdx.x;
    const int w = t >> 6, lane = t & 63, l16 = lane & 15, lg = lane >> 4;
    const int wr = w >> 1, wc = w & 1;           // wave's 64x64 quadrant
    const __hip_bfloat16* xb = xn_t + (size_t)b * HW_ * C_;

    __shared__ __align__(16) __hip_bfloat16 Ab[2][128 * 64];
    __shared__ __align__(16) __hip_bfloat16 Bb[2][128 * 64];

    const int r8  = lane >> 3;           // row within 8-row chunk
    const int ssl = (lane & 7) ^ r8;     // pre-swizzled source slot (16B units)
    auto issue = [&](int kk, int bi) {
        #pragma unroll
        for (int j = 0; j < 4; ++j) {
            const int row = w * 32 + j * 8 + r8;
            gload16(W  + (size_t)(o0 + row) * C_ + kk + ssl * 8, &Ab[bi][(w * 32 + j * 8) * 64]);
            gload16(xb + (size_t)(i0 + row) * C_ + kk + ssl * 8, &Bb[bi][(w * 32 + j * 8) * 64]);
        }
    };

    f32x4 acc[4][4];
    const f32x4 z = {0.f, 0.f, 0.f, 0.f};
    #pragma unroll
    for (int m = 0; m < 4; ++m)
        #pragma unroll
        for (int n = 0; n < 4; ++n) acc[m][n] = z;

    issue(0, 0);
    for (int ks = 0; ks < 8; ++ks) {
        __syncthreads();
        if (ks < 7) issue((ks + 1) * 64, (ks + 1) & 1);
        const __hip_bfloat16* Ac = Ab[ks & 1];
        const __hip_bfloat16* Bc = Bb[ks & 1];
        #pragma unroll
        for (int kks = 0; kks < 2; ++kks) {
            bf16x8 af[4], bfr[4];
            #pragma unroll
            for (int m = 0; m < 4; ++m)
                af[m] = ld8(&Ac[PH_(wr * 64 + m * 16 + l16, kks * 4 + lg)]);
            #pragma unroll
            for (int n = 0; n < 4; ++n)
                bfr[n] = ld8(&Bc[PH_(wc * 64 + n * 16 + l16, kks * 4 + lg)]);
            if (ot < 8) {   // Q/K: swapped -> row=i, col(l16)=d
                #pragma unroll
                for (int m = 0; m < 4; ++m)
                    #pragma unroll
                    for (int n = 0; n < 4; ++n)
                        acc[m][n] = __builtin_amdgcn_mfma_f32_16x16x32_bf16(bfr[n], af[m], acc[m][n], 0, 0, 0);
            } else {        // V: normal -> row=d, col(l16)=i
                #pragma unroll
                for (int m = 0; m < 4; ++m)
                    #pragma unroll
                    for (int n = 0; n < 4; ++n)
                        acc[m][n] = __builtin_amdgcn_mfma_f32_16x16x32_bf16(af[m], bfr[n], acc[m][n], 0, 0, 0);
            }
        }
    }

    if (ot < 4) {            // Q (pre-scaled by SCALE*log2e): row(reg)=i, col(l16)=d
        const int hd = ot;
        __hip_bfloat16* base = q_t + (size_t)(b * NH_ + hd) * HW_ * D_;
        const int dd = wr * 64 + l16;
        #pragma unroll
        for (int m = 0; m < 4; ++m)
            #pragma unroll
            for (int n = 0; n < 4; ++n)
                #pragma unroll
                for (int r = 0; r < 4; ++r) {
                    const int i = i0 + wc * 64 + n * 16 + lg * 4 + r;
                    base[(size_t)i * D_ + dd + m * 16] = __float2bfloat16(acc[m][n][r] * SCALE_L2E_);
                }
    } else if (ot < 8) {     // K
        const int hd = ot - 4;
        __hip_bfloat16* base = k_t + (size_t)(b * NH_ + hd) * HW_ * D_;
        const int dd = wr * 64 + l16;
        #pragma unroll
        for (int m = 0; m < 4; ++m)
            #pragma unroll
            for (int n = 0; n < 4; ++n)
                #pragma unroll
                for (int r = 0; r < 4; ++r) {
                    const int i = i0 + wc * 64 + n * 16 + lg * 4 + r;
                    base[(size_t)i * D_ + dd + m * 16] = __float2bfloat16(acc[m][n][r]);
                }
    } else {                 // V: row(reg)=d, col(l16)=i
        const int hd = ot - 8;
        __hip_bfloat16* base = v_s + (size_t)(b * NH_ + hd) * D_ * HW_;
        #pragma unroll
        for (int m = 0; m < 4; ++m)
            #pragma unroll
            for (int r = 0; r < 4; ++r) {
                const int dd = wr * 64 + m * 16 + lg * 4 + r;
                #pragma unroll
                for (int n = 0; n < 4; ++n) {
                    const int i = i0 + wc * 64 + n * 16 + l16;
                    base[(size_t)dd * HW_ + i] = __float2bfloat16(acc[m][n][r]);
                }
            }
    }
}

// ---------------------------------------------------------------- attention
// 32x32 MFMA, 4 waves x 32 q-rows, swapped QK^T AND swapped PV, in-register
// P via cvt_pk + permlane32_swap (vdst=a, vsrc=b: swaps a.high <-> b.low),
// double-buffered gload_lds staging, full-coverage LDS-repack epilogue.
__global__ __launch_bounds__(256, 2) void attn_kernel(
    const __hip_bfloat16* __restrict__ q_t, const __hip_bfloat16* __restrict__ k_t,
    const __hip_bfloat16* __restrict__ v_s, __hip_bfloat16* __restrict__ at) {
    const int id  = blockIdx.x;            // 0..511
    const int xcd = id & 7;
    const int q8  = id >> 3;               // 0..63
    const int hb  = xcd * 8 + (q8 >> 3);   // all 8 it-tiles of hb on one XCD
    const int it  = q8 & 7;
    const int h   = hb & 3;
    const int b   = hb >> 2;

    const int t = threadIdx.x;
    const int w  = t >> 6;                 // wave 0..3
    const int lane = t & 63;
    const int l32 = lane & 31;             // q within wave tile
    const int hi  = lane >> 5;
    const size_t bh = (size_t)b * NH_ + h;
    const __hip_bfloat16* qp = q_t + bh * HW_ * D_;
    const __hip_bfloat16* kp = k_t + bh * HW_ * D_;
    const __hip_bfloat16* vp = v_s + bh * D_ * HW_;
    const int i0 = it * 128 + w * 32;      // wave's q-base

    // [buf][ kbuf 64x128 (16KB) | vbuf 128x64 (16KB) ]
    __shared__ __align__(16) char smem[2][32768];

    #define KPHYS(row, c) (((row) * 16 + ((c) ^ ((row) & 7))) * 8)
    #define VPHYS(row, c) (((row) * 8  + ((c) ^ ((row) & 7))) * 8)

    const int kri = lane >> 4, ksl = lane & 15;   // K: 4 rows/inst, 16 slots
    const int vri = lane >> 3, vsl = lane & 7;    // V: 8 rows/inst, 8 slots
    auto issue = [&](int j0, int bi) {
        __hip_bfloat16* kb = (__hip_bfloat16*)(smem[bi]);
        __hip_bfloat16* vb = (__hip_bfloat16*)(smem[bi] + 16384);
        #pragma unroll
        for (int i = 0; i < 4; ++i) {
            const int kr = w * 16 + i * 4 + kri;
            gload16(kp + (size_t)(j0 + kr) * D_ + ((ksl ^ (kr & 7)) * 8),
                    kb + (w * 16 + i * 4) * 128);
            const int vr = w * 32 + i * 8 + vri;
            gload16(vp + (size_t)vr * HW_ + j0 + ((vsl ^ (vr & 7)) * 8),
                    vb + (w * 32 + i * 8) * 64);
        }
    };

    // preload Q fragments: lane (q=l32, hi) holds Q[q][ds*16 + hi*8 + 0..7]
    bf16x8 aq[8];
    #pragma unroll
    for (int ds = 0; ds < 8; ++ds)
        aq[ds] = ld8(qp + (size_t)(i0 + l32) * D_ + ds * 16 + hi * 8);

    f32x16 accO[4];
    #pragma unroll
    for (int d = 0; d < 4; ++d)
        #pragma unroll
        for (int e = 0; e < 16; ++e) accO[d][e] = 0.f;
    float m_run = -INFINITY;   // per q-row (q=l32), replicated across hi
    float l_run = 0.f;

    issue(0, 0);

    for (int jb = 0; jb < 16; ++jb) {
        __syncthreads();   // drains current tile's gloads; frees other buffer
        if (jb < 15) issue((jb + 1) * 64, (jb + 1) & 1);
        const __hip_bfloat16* kb = (const __hip_bfloat16*)(smem[jb & 1]);
        const __hip_bfloat16* vb = (const __hip_bfloat16*)(smem[jb & 1] + 16384);

        // ---- swapped QK^T (32x32x16): st[k_local][q], two 32-k tiles
        f32x16 st0, st1;
        #pragma unroll
        for (int e = 0; e < 16; ++e) { st0[e] = 0.f; st1[e] = 0.f; }
        #pragma unroll
        for (int ds = 0; ds < 8; ++ds) {
            bf16x8 kf0 = ld8(&kb[KPHYS(l32,      ds * 2 + hi)]);
            bf16x8 kf1 = ld8(&kb[KPHYS(32 + l32, ds * 2 + hi)]);
            st0 = __builtin_amdgcn_mfma_f32_32x32x16_bf16(kf0, aq[ds], st0, 0, 0, 0);
            st1 = __builtin_amdgcn_mfma_f32_32x32x16_bf16(kf1, aq[ds], st1, 0, 0, 0);
        }

        // ---- row max over 32 in-lane values + cross-hi combine
        float mx = fmaxf(st0[0], st0[1]);
        #pragma unroll
        for (int r = 2; r < 16; ++r) mx = fmaxf(mx, st0[r]);
        #pragma unroll
        for (int r = 0; r < 16; ++r) mx = fmaxf(mx, st1[r]);
        mx = fmaxf(mx, __shfl_xor(mx, 32, 64));

        // ---- defer-max (THR=8, exp2 domain); alpha is pure per-lane scalar
        if (__any(mx > m_run + 8.f)) {
            float mnew = fmaxf(m_run, mx);
            float alpha = exp2f(m_run - mnew);   // 0 on first tile
            m_run = mnew;
            l_run *= alpha;
            #pragma unroll
            for (int d = 0; d < 4; ++d)
                #pragma unroll
                for (int e = 0; e < 16; ++e) accO[d][e] *= alpha;
        }

        // ---- P = exp2(S - m), sum
        float p0[16], p1[16];
        float sum = 0.f;
        #pragma unroll
        for (int r = 0; r < 16; ++r) { p0[r] = exp2f(st0[r] - m_run); sum += p0[r]; }
        #pragma unroll
        for (int r = 0; r < 16; ++r) { p1[r] = exp2f(st1[r] - m_run); sum += p1[r]; }
        sum += __shfl_xor(sum, 32, 64);
        l_run += sum;

        // ---- PV (swapped: A=V, B=P in-register)
        // p[reg] = P[k_local=(reg&3)+8*(reg>>2)+4*hi][q=l32]
        // B-frag word layout (verified m214 recipe): swap(a,b) with vdst=a:
        //   new a = {a.low, b.low^}, new b = {a.high_v, b.high}
        #define PV_STEP(PARR, KS) do {                                          \
            const int g0 = ((KS) & 1) * 2;                                      \
            unsigned a0 = cvtpk_bf16(PARR[g0 * 4 + 0], PARR[g0 * 4 + 1]);       \
            unsigned a1 = cvtpk_bf16(PARR[g0 * 4 + 2], PARR[g0 * 4 + 3]);       \
            unsigned b0 = cvtpk_bf16(PARR[g0 * 4 + 4], PARR[g0 * 4 + 5]);       \
            unsigned b1 = cvtpk_bf16(PARR[g0 * 4 + 6], PARR[g0 * 4 + 7]);       \
            asm volatile("v_permlane32_swap_b32 %0, %1" : "+v"(a0), "+v"(b0));  \
            asm volatile("v_permlane32_swap_b32 %0, %1" : "+v"(a1), "+v"(b1));  \
            union { unsigned u[4]; bf16x8 v; } pf;                              \
            pf.u[0] = a0; pf.u[1] = a1; pf.u[2] = b0; pf.u[3] = b1;             \
            _Pragma("unroll")                                                   \
            for (int dt = 0; dt < 4; ++dt) {                                    \
                bf16x8 vf = ld8(&vb[VPHYS(dt * 32 + l32, (KS) * 2 + hi)]);      \
                accO[dt] = __builtin_amdgcn_mfma_f32_32x32x16_bf16(              \
                    vf, pf.v, accO[dt], 0, 0, 0);                               \
            }                                                                   \
        } while (0)
        PV_STEP(p0, 0);
        PV_STEP(p0, 1);
        PV_STEP(p1, 2);
        PV_STEP(p1, 3);
        #undef PV_STEP
    }

    // ---- epilogue: normalize, repack via LDS, coalesced full-coverage store
    __syncthreads();   // staging buffers dead; reuse smem
    const float linv = 1.f / l_run;
    __hip_bfloat16* Ep = (__hip_bfloat16*)smem + w * (32 * 132);
    #pragma unroll
    for (int dt = 0; dt < 4; ++dt)
        #pragma unroll
        for (int r = 0; r < 16; ++r) {
            const int d = dt * 32 + (r & 3) + 4 * hi + 8 * (r >> 2);
            Ep[l32 * 132 + d] = __float2bfloat16(accO[dt][r] * linv);
        }
    // same-wave LDS RAW ordered via lgkmcnt
    __hip_bfloat16* ob = at + ((size_t)b * HW_ + i0) * C_ + h * D_;
    #pragma unroll
    for (int rr = 0; rr < 8; ++rr) {
        const int row = rr * 4 + (lane >> 4);
        const int col = (lane & 15) * 8;
        bf16x8 vv = ld8(&Ep[row * 132 + col]);
        *reinterpret_cast<bf16x8*>(ob + (size_t)row * C_ + col) = vv;
    }
    #undef KPHYS
    #undef VPHYS
}

// ---------------------------------------------------------------- out GEMM + bias + residual
__global__ __launch_bounds__(256, 2) void out_gemm(
    const __hip_bfloat16* __restrict__ W, const __hip_bfloat16* __restrict__ at,
    const float* __restrict__ b_out, const float* __restrict__ x,
    float* __restrict__ out) {
    const int id   = blockIdx.x;                // 0..511
    const int virt = (id & 7) * 64 + (id >> 3); // XCD-chunked remap
    const int ot   = virt & 3;
    const int rest = virt >> 2;
    const int itl  = rest & 7;
    const int b    = rest >> 3;
    const int o0 = ot * 128, i0 = itl * 128;

    const int t = threadIdx.x;
    const int w = t >> 6, lane = t & 63, l16 = lane & 15, lg = lane >> 4;
    const int wr = w >> 1, wc = w & 1;
    const __hip_bfloat16* ab = at + (size_t)b * HW_ * C_;

    __shared__ __align__(16) __hip_bfloat16 Ab[2][128 * 64];
    __shared__ __align__(16) __hip_bfloat16 Bb[2][128 * 64];

    const int r8  = lane >> 3;
    const int ssl = (lane & 7) ^ r8;
    auto issue = [&](int kk, int bi) {
        #pragma unroll
        for (int j = 0; j < 4; ++j) {
            const int row = w * 32 + j * 8 + r8;
            gload16(W  + (size_t)(o0 + row) * C_ + kk + ssl * 8, &Ab[bi][(w * 32 + j * 8) * 64]);
            gload16(ab + (size_t)(i0 + row) * C_ + kk + ssl * 8, &Bb[bi][(w * 32 + j * 8) * 64]);
        }
    };

    f32x4 acc[4][4];
    const f32x4 z = {0.f, 0.f, 0.f, 0.f};
    #pragma unroll
    for (int m = 0; m < 4; ++m)
        #pragma unroll
        for (int n = 0; n < 4; ++n) acc[m][n] = z;

    issue(0, 0);
    for (int ks = 0; ks < 8; ++ks) {
        __syncthreads();
        if (ks < 7) issue((ks + 1) * 64, (ks + 1) & 1);
        const __hip_bfloat16* Ac = Ab[ks & 1];
        const __hip_bfloat16* Bc = Bb[ks & 1];
        #pragma unroll
        for (int kks = 0; kks < 2; ++kks) {
            bf16x8 af[4], bfr[4];
            #pragma unroll
            for (int m = 0; m < 4; ++m)
                af[m] = ld8(&Ac[PH_(wr * 64 + m * 16 + l16, kks * 4 + lg)]);
            #pragma unroll
            for (int n = 0; n < 4; ++n)
                bfr[n] = ld8(&Bc[PH_(wc * 64 + n * 16 + l16, kks * 4 + lg)]);
            #pragma unroll
            for (int m = 0; m < 4; ++m)
                #pragma unroll
                for (int n = 0; n < 4; ++n)
                    acc[m][n] = __builtin_amdgcn_mfma_f32_16x16x32_bf16(af[m], bfr[n], acc[m][n], 0, 0, 0);
        }
    }

    #pragma unroll
    for (int m = 0; m < 4; ++m)
        #pragma unroll
        for (int r = 0; r < 4; ++r) {
            const int o = o0 + wr * 64 + m * 16 + lg * 4 + r;
            const float bo = b_out[o];
            #pragma unroll
            for (int n = 0; n < 4; ++n) {
                const int i = i0 + wc * 64 + n * 16 + l16;
                const size_t idx = ((size_t)(b * C_ + o)) * HW_ + i;
                out[idx] = acc[m][n][r] + bo + x[idx];
            }
        }
}

// ---------------------------------------------------------------- launch
extern "C" void kernel_launch(void* const* d_in, const int* in_sizes, int n_in,
                              void* d_out, int out_size, void* d_ws, size_t ws_size,
                              hipStream_t stream) {
    (void)in_sizes; (void)n_in; (void)out_size; (void)ws_size;
    const float* x     = (const float*)d_in[0];
    const float* gn_w  = (const float*)d_in[1];
    const float* gn_b  = (const float*)d_in[2];
    const float* w_qkv = (const float*)d_in[3];
    const float* w_out = (const float*)d_in[4];
    const float* b_out = (const float*)d_in[5];
    float* out = (float*)d_out;

    char* ws = (char*)d_ws;
    size_t off = 0;
    auto alloc = [&](size_t bytes) { void* p = ws + off; off += (bytes + 255) & ~255ULL; return p; };
    __hip_bfloat16* wqkv_bf = (__hip_bfloat16*)alloc((size_t)3 * C_ * C_ * 2);
    __hip_bfloat16* wout_bf = (__hip_bfloat16*)alloc((size_t)C_ * C_ * 2);
    __hip_bfloat16* xn_t    = (__hip_bfloat16*)alloc((size_t)B_ * HW_ * C_ * 2);
    __hip_bfloat16* q_t     = (__hip_bfloat16*)alloc((size_t)B_ * HW_ * C_ * 2);
    __hip_bfloat16* k_t     = (__hip_bfloat16*)alloc((size_t)B_ * HW_ * C_ * 2);
    __hip_bfloat16* v_s     = (__hip_bfloat16*)alloc((size_t)B_ * HW_ * C_ * 2);
    __hip_bfloat16* at      = xn_t;  // alias: xn_t dead after qkv_gemm

    convert_w<<<768, 256, 0, stream>>>(w_qkv, w_out, wqkv_bf, wout_bf);
    gn_kernel<<<512, 256, 0, stream>>>(x, gn_w, gn_b, xn_t);
    qkv_gemm<<<1536, 256, 0, stream>>>(wqkv_bf, xn_t, q_t, k_t, v_s);
    attn_kernel<<<512, 256, 0, stream>>>(q_t, k_t, v_s, at);
    out_gemm<<<512, 256, 0, stream>>>(wout_bf, at, b_out, x, out);
}

// Round 14
// 123.303 us; speedup vs baseline: 1.0727x; 1.0138x over previous
//
#include <hip/hip_runtime.h>
#include <hip/hip_bf16.h>

// Problem constants
#define B_    16
#define C_    512
#define HW_   1024
#define G_    32
#define CPG_  16      // channels per group
#define NH_   4
#define D_    128
#define EPS_  1e-5f
#define SCALE_ 0.08838834764831845f       // 1/sqrt(128)
#define SCALE_L2E_ 0.1275174306f          // SCALE_ * log2(e): softmax done in exp2

typedef short bf16x8 __attribute__((ext_vector_type(8)));
typedef short bf16x4 __attribute__((ext_vector_type(4)));
typedef float f32x4  __attribute__((ext_vector_type(4)));
typedef float f32x16 __attribute__((ext_vector_type(16)));

typedef __attribute__((address_space(3))) unsigned int lds_u32_t;
typedef const __attribute__((address_space(1))) unsigned int glb_u32_t;

__device__ __forceinline__ bf16x8 ld8(const __hip_bfloat16* p) {
    return *reinterpret_cast<const bf16x8*>(p);
}
__device__ __forceinline__ void gload16(const __hip_bfloat16* g, __hip_bfloat16* l) {
    __builtin_amdgcn_global_load_lds((glb_u32_t*)(const void*)g,
                                     (lds_u32_t*)(void*)l, 16, 0, 0);
}
__device__ __forceinline__ unsigned cvtpk_bf16(float lo, float hi) {
    unsigned r;
    asm("v_cvt_pk_bf16_f32 %0, %1, %2" : "=v"(r) : "v"(lo), "v"(hi));
    return r;
}

// ---------------------------------------------------------------- weights
__global__ __launch_bounds__(256) void convert_w(
    const float* __restrict__ wqkv, const float* __restrict__ wout,
    __hip_bfloat16* __restrict__ wqkv_bf, __hip_bfloat16* __restrict__ wout_bf) {
    const int i = (blockIdx.x * 256 + threadIdx.x) * 4;
    if (i < 3 * C_ * C_) {
        float4 v = *reinterpret_cast<const float4*>(wqkv + i);
        union { bf16x4 s; __hip_bfloat16 h[4]; } u;
        u.h[0] = __float2bfloat16(v.x); u.h[1] = __float2bfloat16(v.y);
        u.h[2] = __float2bfloat16(v.z); u.h[3] = __float2bfloat16(v.w);
        *reinterpret_cast<bf16x4*>(wqkv_bf + i) = u.s;
    }
    if (i < C_ * C_) {
        float4 v = *reinterpret_cast<const float4*>(wout + i);
        union { bf16x4 s; __hip_bfloat16 h[4]; } u;
        u.h[0] = __float2bfloat16(v.x); u.h[1] = __float2bfloat16(v.y);
        u.h[2] = __float2bfloat16(v.z); u.h[3] = __float2bfloat16(v.w);
        *reinterpret_cast<bf16x4*>(wout_bf + i) = u.s;
    }
}

// ---------------------------------------------------------------- groupnorm
__global__ __launch_bounds__(256) void gn_kernel(
    const float* __restrict__ x, const float* __restrict__ gnw,
    const float* __restrict__ gnb, __hip_bfloat16* __restrict__ xn_t) {
    const int b = blockIdx.x >> 5;
    const int g = blockIdx.x & 31;
    const float* xp = x + ((size_t)(b * C_ + g * CPG_)) * HW_;  // 16x1024 contiguous

    float s = 0.f, s2 = 0.f;
    const float4* xv = reinterpret_cast<const float4*>(xp);
    #pragma unroll
    for (int t = 0; t < 16; ++t) {
        float4 v = xv[threadIdx.x + t * 256];
        s  += v.x + v.y + v.z + v.w;
        s2 += v.x * v.x + v.y * v.y + v.z * v.z + v.w * v.w;
    }
    #pragma unroll
    for (int off = 32; off > 0; off >>= 1) {
        s  += __shfl_down(s,  off, 64);
        s2 += __shfl_down(s2, off, 64);
    }
    __shared__ float ss[4], ss2[4];
    if ((threadIdx.x & 63) == 0) { ss[threadIdx.x >> 6] = s; ss2[threadIdx.x >> 6] = s2; }
    __syncthreads();
    s = ss[0] + ss[1] + ss[2] + ss[3];
    s2 = ss2[0] + ss2[1] + ss2[2] + ss2[3];
    const float mean = s * (1.f / 16384.f);
    const float inv  = rsqrtf(fmaxf(s2 * (1.f / 16384.f) - mean * mean, 0.f) + EPS_);

    float a[16], bb[16];
    #pragma unroll
    for (int cc = 0; cc < 16; ++cc) {
        float w = gnw[g * CPG_ + cc];
        a[cc] = inv * w;
        bb[cc] = gnb[g * CPG_ + cc] - mean * inv * w;
    }

    for (int hw = threadIdx.x; hw < HW_; hw += 256) {
        union { bf16x8 v; __hip_bfloat16 h[8]; } u0, u1;
        #pragma unroll
        for (int cc = 0; cc < 8; ++cc)
            u0.h[cc] = __float2bfloat16(xp[cc * HW_ + hw] * a[cc] + bb[cc]);
        #pragma unroll
        for (int cc = 8; cc < 16; ++cc)
            u1.h[cc - 8] = __float2bfloat16(xp[cc * HW_ + hw] * a[cc] + bb[cc]);
        __hip_bfloat16* dst = xn_t + ((size_t)(b * HW_ + hw)) * C_ + g * CPG_;
        *reinterpret_cast<bf16x8*>(dst) = u0.v;
        *reinterpret_cast<bf16x8*>(dst + 8) = u1.v;
    }
}

// swizzled phys element offset: 128-row tile, 8 slots (16B) per row
#define PH_(r, s) (((r) * 8 + ((s) ^ ((r) & 7))) * 8)

// ---------------------------------------------------------------- QKV GEMM
// Double-buffered gload_lds staging (T3 2-phase).
__global__ __launch_bounds__(256, 2) void qkv_gemm(
    const __hip_bfloat16* __restrict__ W, const __hip_bfloat16* __restrict__ xn_t,
    __hip_bfloat16* __restrict__ q_t, __hip_bfloat16* __restrict__ k_t,
    __hip_bfloat16* __restrict__ v_s) {
    const int id   = blockIdx.x;                 // 0..1535
    const int virt = (id & 7) * 192 + (id >> 3); // XCD-chunked remap
    const int ot   = virt % 12;                  // o tile (0-3 Q, 4-7 K, 8-11 V)
    const int rest = virt / 12;
    const int itl  = rest & 7;
    const int b    = rest >> 3;
    const int o0 = ot * 128, i0 = itl * 128;

    const int t = threadIdx.x;
    const int w = t >> 6, lane = t & 63, l16 = lane & 15, lg = lane >> 4;
    const int wr = w >> 1, wc = w & 1;           // wave's 64x64 quadrant
    const __hip_bfloat16* xb = xn_t + (size_t)b * HW_ * C_;

    __shared__ __align__(16) __hip_bfloat16 Ab[2][128 * 64];
    __shared__ __align__(16) __hip_bfloat16 Bb[2][128 * 64];

    const int r8  = lane >> 3;           // row within 8-row chunk
    const int ssl = (lane & 7) ^ r8;     // pre-swizzled source slot (16B units)
    auto issue = [&](int kk, int bi) {
        #pragma unroll
        for (int j = 0; j < 4; ++j) {
            const int row = w * 32 + j * 8 + r8;
            gload16(W  + (size_t)(o0 + row) * C_ + kk + ssl * 8, &Ab[bi][(w * 32 + j * 8) * 64]);
            gload16(xb + (size_t)(i0 + row) * C_ + kk + ssl * 8, &Bb[bi][(w * 32 + j * 8) * 64]);
        }
    };

    f32x4 acc[4][4];
    const f32x4 z = {0.f, 0.f, 0.f, 0.f};
    #pragma unroll
    for (int m = 0; m < 4; ++m)
        #pragma unroll
        for (int n = 0; n < 4; ++n) acc[m][n] = z;

    issue(0, 0);
    for (int ks = 0; ks < 8; ++ks) {
        __syncthreads();
        if (ks < 7) issue((ks + 1) * 64, (ks + 1) & 1);
        const __hip_bfloat16* Ac = Ab[ks & 1];
        const __hip_bfloat16* Bc = Bb[ks & 1];
        #pragma unroll
        for (int kks = 0; kks < 2; ++kks) {
            bf16x8 af[4], bfr[4];
            #pragma unroll
            for (int m = 0; m < 4; ++m)
                af[m] = ld8(&Ac[PH_(wr * 64 + m * 16 + l16, kks * 4 + lg)]);
            #pragma unroll
            for (int n = 0; n < 4; ++n)
                bfr[n] = ld8(&Bc[PH_(wc * 64 + n * 16 + l16, kks * 4 + lg)]);
            if (ot < 8) {   // Q/K: swapped -> row=i, col(l16)=d
                #pragma unroll
                for (int m = 0; m < 4; ++m)
                    #pragma unroll
                    for (int n = 0; n < 4; ++n)
                        acc[m][n] = __builtin_amdgcn_mfma_f32_16x16x32_bf16(bfr[n], af[m], acc[m][n], 0, 0, 0);
            } else {        // V: normal -> row=d, col(l16)=i
                #pragma unroll
                for (int m = 0; m < 4; ++m)
                    #pragma unroll
                    for (int n = 0; n < 4; ++n)
                        acc[m][n] = __builtin_amdgcn_mfma_f32_16x16x32_bf16(af[m], bfr[n], acc[m][n], 0, 0, 0);
            }
        }
    }

    if (ot < 4) {            // Q (pre-scaled by SCALE*log2e): row(reg)=i, col(l16)=d
        const int hd = ot;
        __hip_bfloat16* base = q_t + (size_t)(b * NH_ + hd) * HW_ * D_;
        const int dd = wr * 64 + l16;
        #pragma unroll
        for (int m = 0; m < 4; ++m)
            #pragma unroll
            for (int n = 0; n < 4; ++n)
                #pragma unroll
                for (int r = 0; r < 4; ++r) {
                    const int i = i0 + wc * 64 + n * 16 + lg * 4 + r;
                    base[(size_t)i * D_ + dd + m * 16] = __float2bfloat16(acc[m][n][r] * SCALE_L2E_);
                }
    } else if (ot < 8) {     // K
        const int hd = ot - 4;
        __hip_bfloat16* base = k_t + (size_t)(b * NH_ + hd) * HW_ * D_;
        const int dd = wr * 64 + l16;
        #pragma unroll
        for (int m = 0; m < 4; ++m)
            #pragma unroll
            for (int n = 0; n < 4; ++n)
                #pragma unroll
                for (int r = 0; r < 4; ++r) {
                    const int i = i0 + wc * 64 + n * 16 + lg * 4 + r;
                    base[(size_t)i * D_ + dd + m * 16] = __float2bfloat16(acc[m][n][r]);
                }
    } else {                 // V: row(reg)=d, col(l16)=i
        const int hd = ot - 8;
        __hip_bfloat16* base = v_s + (size_t)(b * NH_ + hd) * D_ * HW_;
        #pragma unroll
        for (int m = 0; m < 4; ++m)
            #pragma unroll
            for (int r = 0; r < 4; ++r) {
                const int dd = wr * 64 + m * 16 + lg * 4 + r;
                #pragma unroll
                for (int n = 0; n < 4; ++n) {
                    const int i = i0 + wc * 64 + n * 16 + l16;
                    base[(size_t)dd * HW_ + i] = __float2bfloat16(acc[m][n][r]);
                }
            }
    }
}

// ---------------------------------------------------------------- attention
// 32x32 MFMA, 8 waves x 32 q-rows (256 q/block -> 2x waves share the K/V
// tile), swapped QK^T AND swapped PV, in-register P via cvt_pk+permlane32,
// double-buffered gload_lds staging, two-pass LDS-repack epilogue.
__global__ __launch_bounds__(512, 2) void attn_kernel(
    const __hip_bfloat16* __restrict__ q_t, const __hip_bfloat16* __restrict__ k_t,
    const __hip_bfloat16* __restrict__ v_s, __hip_bfloat16* __restrict__ at) {
    const int id  = blockIdx.x;            // 0..255
    const int xcd = id & 7;
    const int q8  = id >> 3;               // 0..31
    const int hb  = xcd * 8 + (q8 >> 2);   // all 4 it-tiles of hb on one XCD
    const int it  = q8 & 3;
    const int h   = hb & 3;
    const int b   = hb >> 2;

    const int t = threadIdx.x;
    const int w  = t >> 6;                 // wave 0..7
    const int lane = t & 63;
    const int l32 = lane & 31;             // q within wave tile
    const int hi  = lane >> 5;
    const size_t bh = (size_t)b * NH_ + h;
    const __hip_bfloat16* qp = q_t + bh * HW_ * D_;
    const __hip_bfloat16* kp = k_t + bh * HW_ * D_;
    const __hip_bfloat16* vp = v_s + bh * D_ * HW_;
    const int i0 = it * 256 + w * 32;      // wave's q-base

    // [buf][ kbuf 64x128 (16KB) | vbuf 128x64 (16KB) ]
    __shared__ __align__(16) char smem[2][32768];

    #define KPHYS(row, c) (((row) * 16 + ((c) ^ ((row) & 7))) * 8)
    #define VPHYS(row, c) (((row) * 8  + ((c) ^ ((row) & 7))) * 8)

    const int kri = lane >> 4, ksl = lane & 15;   // K: 4 rows/inst, 16 slots
    const int vri = lane >> 3, vsl = lane & 7;    // V: 8 rows/inst, 8 slots
    auto issue = [&](int j0, int bi) {
        __hip_bfloat16* kb = (__hip_bfloat16*)(smem[bi]);
        __hip_bfloat16* vb = (__hip_bfloat16*)(smem[bi] + 16384);
        #pragma unroll
        for (int i = 0; i < 2; ++i) {
            const int kr = w * 8 + i * 4 + kri;
            gload16(kp + (size_t)(j0 + kr) * D_ + ((ksl ^ (kr & 7)) * 8),
                    kb + (w * 8 + i * 4) * 128);
            const int vr = w * 16 + i * 8 + vri;
            gload16(vp + (size_t)vr * HW_ + j0 + ((vsl ^ (vr & 7)) * 8),
                    vb + (w * 16 + i * 8) * 64);
        }
    };

    // preload Q fragments: lane (q=l32, hi) holds Q[q][ds*16 + hi*8 + 0..7]
    bf16x8 aq[8];
    #pragma unroll
    for (int ds = 0; ds < 8; ++ds)
        aq[ds] = ld8(qp + (size_t)(i0 + l32) * D_ + ds * 16 + hi * 8);

    f32x16 accO[4];
    #pragma unroll
    for (int d = 0; d < 4; ++d)
        #pragma unroll
        for (int e = 0; e < 16; ++e) accO[d][e] = 0.f;
    float m_run = -INFINITY;   // per q-row (q=l32), replicated across hi
    float l_run = 0.f;

    issue(0, 0);

    for (int jb = 0; jb < 16; ++jb) {
        __syncthreads();   // drains current tile's gloads; frees other buffer
        if (jb < 15) issue((jb + 1) * 64, (jb + 1) & 1);
        const __hip_bfloat16* kb = (const __hip_bfloat16*)(smem[jb & 1]);
        const __hip_bfloat16* vb = (const __hip_bfloat16*)(smem[jb & 1] + 16384);

        // ---- swapped QK^T (32x32x16): st[k_local][q], two 32-k tiles
        f32x16 st0, st1;
        #pragma unroll
        for (int e = 0; e < 16; ++e) { st0[e] = 0.f; st1[e] = 0.f; }
        #pragma unroll
        for (int ds = 0; ds < 8; ++ds) {
            bf16x8 kf0 = ld8(&kb[KPHYS(l32,      ds * 2 + hi)]);
            bf16x8 kf1 = ld8(&kb[KPHYS(32 + l32, ds * 2 + hi)]);
            st0 = __builtin_amdgcn_mfma_f32_32x32x16_bf16(kf0, aq[ds], st0, 0, 0, 0);
            st1 = __builtin_amdgcn_mfma_f32_32x32x16_bf16(kf1, aq[ds], st1, 0, 0, 0);
        }

        // ---- row max over 32 in-lane values + cross-hi combine
        float mx = fmaxf(st0[0], st0[1]);
        #pragma unroll
        for (int r = 2; r < 16; ++r) mx = fmaxf(mx, st0[r]);
        #pragma unroll
        for (int r = 0; r < 16; ++r) mx = fmaxf(mx, st1[r]);
        mx = fmaxf(mx, __shfl_xor(mx, 32, 64));

        // ---- defer-max (THR=8, exp2 domain); alpha is pure per-lane scalar
        if (__any(mx > m_run + 8.f)) {
            float mnew = fmaxf(m_run, mx);
            float alpha = exp2f(m_run - mnew);   // 0 on first tile
            m_run = mnew;
            l_run *= alpha;
            #pragma unroll
            for (int d = 0; d < 4; ++d)
                #pragma unroll
                for (int e = 0; e < 16; ++e) accO[d][e] *= alpha;
        }

        // ---- P = exp2(S - m), sum
        float p0[16], p1[16];
        float sum = 0.f;
        #pragma unroll
        for (int r = 0; r < 16; ++r) { p0[r] = exp2f(st0[r] - m_run); sum += p0[r]; }
        #pragma unroll
        for (int r = 0; r < 16; ++r) { p1[r] = exp2f(st1[r] - m_run); sum += p1[r]; }
        sum += __shfl_xor(sum, 32, 64);
        l_run += sum;

        // ---- PV (swapped: A=V, B=P in-register)
        #define PV_STEP(PARR, KS) do {                                          \
            const int g0 = ((KS) & 1) * 2;                                      \
            unsigned a0 = cvtpk_bf16(PARR[g0 * 4 + 0], PARR[g0 * 4 + 1]);       \
            unsigned a1 = cvtpk_bf16(PARR[g0 * 4 + 2], PARR[g0 * 4 + 3]);       \
            unsigned b0 = cvtpk_bf16(PARR[g0 * 4 + 4], PARR[g0 * 4 + 5]);       \
            unsigned b1 = cvtpk_bf16(PARR[g0 * 4 + 6], PARR[g0 * 4 + 7]);       \
            asm volatile("v_permlane32_swap_b32 %0, %1" : "+v"(a0), "+v"(b0));  \
            asm volatile("v_permlane32_swap_b32 %0, %1" : "+v"(a1), "+v"(b1));  \
            union { unsigned u[4]; bf16x8 v; } pf;                              \
            pf.u[0] = a0; pf.u[1] = a1; pf.u[2] = b0; pf.u[3] = b1;             \
            _Pragma("unroll")                                                   \
            for (int dt = 0; dt < 4; ++dt) {                                    \
                bf16x8 vf = ld8(&vb[VPHYS(dt * 32 + l32, (KS) * 2 + hi)]);      \
                accO[dt] = __builtin_amdgcn_mfma_f32_32x32x16_bf16(              \
                    vf, pf.v, accO[dt], 0, 0, 0);                               \
            }                                                                   \
        } while (0)
        PV_STEP(p0, 0);
        PV_STEP(p0, 1);
        PV_STEP(p1, 2);
        PV_STEP(p1, 3);
        #undef PV_STEP
    }

    // ---- epilogue: normalize, two-pass repack via LDS (4 waves per pass),
    // coalesced full-coverage store
    const float linv = 1.f / l_run;
    __hip_bfloat16* ob = at + ((size_t)b * HW_ + i0) * C_ + h * D_;
    __syncthreads();   // staging buffers dead; reuse smem
    #pragma unroll
    for (int pass = 0; pass < 2; ++pass) {
        if ((w >> 2) == pass) {
            __hip_bfloat16* Ep = (__hip_bfloat16*)smem + (w & 3) * (32 * 132);
            #pragma unroll
            for (int dt = 0; dt < 4; ++dt)
                #pragma unroll
                for (int r = 0; r < 16; ++r) {
                    const int d = dt * 32 + (r & 3) + 4 * hi + 8 * (r >> 2);
                    Ep[l32 * 132 + d] = __float2bfloat16(accO[dt][r] * linv);
                }
            // same-wave LDS RAW ordered via lgkmcnt
            #pragma unroll
            for (int rr = 0; rr < 8; ++rr) {
                const int row = rr * 4 + (lane >> 4);
                const int col = (lane & 15) * 8;
                bf16x8 vv = ld8(&Ep[row * 132 + col]);
                *reinterpret_cast<bf16x8*>(ob + (size_t)row * C_ + col) = vv;
            }
        }
        __syncthreads();
    }
    #undef KPHYS
    #undef VPHYS
}

// ---------------------------------------------------------------- out GEMM + bias + residual
__global__ __launch_bounds__(256, 2) void out_gemm(
    const __hip_bfloat16* __restrict__ W, const __hip_bfloat16* __restrict__ at,
    const float* __restrict__ b_out, const float* __restrict__ x,
    float* __restrict__ out) {
    const int id   = blockIdx.x;                // 0..511
    const int virt = (id & 7) * 64 + (id >> 3); // XCD-chunked remap
    const int ot   = virt & 3;
    const int rest = virt >> 2;
    const int itl  = rest & 7;
    const int b    = rest >> 3;
    const int o0 = ot * 128, i0 = itl * 128;

    const int t = threadIdx.x;
    const int w = t >> 6, lane = t & 63, l16 = lane & 15, lg = lane >> 4;
    const int wr = w >> 1, wc = w & 1;
    const __hip_bfloat16* ab = at + (size_t)b * HW_ * C_;

    __shared__ __align__(16) __hip_bfloat16 Ab[2][128 * 64];
    __shared__ __align__(16) __hip_bfloat16 Bb[2][128 * 64];

    const int r8  = lane >> 3;
    const int ssl = (lane & 7) ^ r8;
    auto issue = [&](int kk, int bi) {
        #pragma unroll
        for (int j = 0; j < 4; ++j) {
            const int row = w * 32 + j * 8 + r8;
            gload16(W  + (size_t)(o0 + row) * C_ + kk + ssl * 8, &Ab[bi][(w * 32 + j * 8) * 64]);
            gload16(ab + (size_t)(i0 + row) * C_ + kk + ssl * 8, &Bb[bi][(w * 32 + j * 8) * 64]);
        }
    };

    f32x4 acc[4][4];
    const f32x4 z = {0.f, 0.f, 0.f, 0.f};
    #pragma unroll
    for (int m = 0; m < 4; ++m)
        #pragma unroll
        for (int n = 0; n < 4; ++n) acc[m][n] = z;

    issue(0, 0);
    for (int ks = 0; ks < 8; ++ks) {
        __syncthreads();
        if (ks < 7) issue((ks + 1) * 64, (ks + 1) & 1);
        const __hip_bfloat16* Ac = Ab[ks & 1];
        const __hip_bfloat16* Bc = Bb[ks & 1];
        #pragma unroll
        for (int kks = 0; kks < 2; ++kks) {
            bf16x8 af[4], bfr[4];
            #pragma unroll
            for (int m = 0; m < 4; ++m)
                af[m] = ld8(&Ac[PH_(wr * 64 + m * 16 + l16, kks * 4 + lg)]);
            #pragma unroll
            for (int n = 0; n < 4; ++n)
                bfr[n] = ld8(&Bc[PH_(wc * 64 + n * 16 + l16, kks * 4 + lg)]);
            #pragma unroll
            for (int m = 0; m < 4; ++m)
                #pragma unroll
                for (int n = 0; n < 4; ++n)
                    acc[m][n] = __builtin_amdgcn_mfma_f32_16x16x32_bf16(af[m], bfr[n], acc[m][n], 0, 0, 0);
        }
    }

    #pragma unroll
    for (int m = 0; m < 4; ++m)
        #pragma unroll
        for (int r = 0; r < 4; ++r) {
            const int o = o0 + wr * 64 + m * 16 + lg * 4 + r;
            const float bo = b_out[o];
            #pragma unroll
            for (int n = 0; n < 4; ++n) {
                const int i = i0 + wc * 64 + n * 16 + l16;
                const size_t idx = ((size_t)(b * C_ + o)) * HW_ + i;
                out[idx] = acc[m][n][r] + bo + x[idx];
            }
        }
}

// ---------------------------------------------------------------- launch
extern "C" void kernel_launch(void* const* d_in, const int* in_sizes, int n_in,
                              void* d_out, int out_size, void* d_ws, size_t ws_size,
                              hipStream_t stream) {
    (void)in_sizes; (void)n_in; (void)out_size; (void)ws_size;
    const float* x     = (const float*)d_in[0];
    const float* gn_w  = (const float*)d_in[1];
    const float* gn_b  = (const float*)d_in[2];
    const float* w_qkv = (const float*)d_in[3];
    const float* w_out = (const float*)d_in[4];
    const float* b_out = (const float*)d_in[5];
    float* out = (float*)d_out;

    char* ws = (char*)d_ws;
    size_t off = 0;
    auto alloc = [&](size_t bytes) { void* p = ws + off; off += (bytes + 255) & ~255ULL; return p; };
    __hip_bfloat16* wqkv_bf = (__hip_bfloat16*)alloc((size_t)3 * C_ * C_ * 2);
    __hip_bfloat16* wout_bf = (__hip_bfloat16*)alloc((size_t)C_ * C_ * 2);
    __hip_bfloat16* xn_t    = (__hip_bfloat16*)alloc((size_t)B_ * HW_ * C_ * 2);
    __hip_bfloat16* q_t     = (__hip_bfloat16*)alloc((size_t)B_ * HW_ * C_ * 2);
    __hip_bfloat16* k_t     = (__hip_bfloat16*)alloc((size_t)B_ * HW_ * C_ * 2);
    __hip_bfloat16* v_s     = (__hip_bfloat16*)alloc((size_t)B_ * HW_ * C_ * 2);
    __hip_bfloat16* at      = xn_t;  // alias: xn_t dead after qkv_gemm

    convert_w<<<768, 256, 0, stream>>>(w_qkv, w_out, wqkv_bf, wout_bf);
    gn_kernel<<<512, 256, 0, stream>>>(x, gn_w, gn_b, xn_t);
    qkv_gemm<<<1536, 256, 0, stream>>>(wqkv_bf, xn_t, q_t, k_t, v_s);
    attn_kernel<<<256, 512, 0, stream>>>(q_t, k_t, v_s, at);
    out_gemm<<<512, 256, 0, stream>>>(wout_bf, at, b_out, x, out);
}